// Round 12
// baseline (299.287 us; speedup 1.0000x reference)
//
#include <hip/hip_runtime.h>

// Problem constants (B=64, T=4096, D=100, K=4, BETA=0.25)
#define D_DIM   100
#define K_CODES 4
#define N_ROWS  262144  // B*T
#define TAU     0.5f    // f32 d2 margin below which we recompute exactly
#define GEMM_TPB 512    // 8 waves
#define GEMM_GRID 512   // 4096 waves x 4 tiles x 16 rows = 262144
#define TILES_PER_WAVE 4
#define NB_PAD  112     // padded W cols (7 col-tiles of 16)

typedef __attribute__((ext_vector_type(8))) __bf16 bf16x8;
typedef __attribute__((ext_vector_type(4))) float  f32x4;

__device__ __forceinline__ unsigned short f2bf_rne(float f) {
    unsigned int u = __builtin_bit_cast(unsigned int, f);
    unsigned int r = u + 0x7fffu + ((u >> 16) & 1u);
    return (unsigned short)(r >> 16);
}
__device__ __forceinline__ float bf2f(unsigned short b) {
    unsigned int u = ((unsigned int)b) << 16;
    return __builtin_bit_cast(float, u);
}

// R6-proven exact recompute (R1 arithmetic) for global row gr; wave-cooperative.
// Returns exact argmin index (valid in all lanes).
__device__ __forceinline__ int exact_row_argmin(
    const float* __restrict__ x, const float* __restrict__ W1,
    const float* __restrict__ b1, const float* __restrict__ cb,
    int gr, int lane)
{
    const int e1 = lane;
    const int e2 = 64 + lane;
    const bool has2 = (e2 < D_DIM);
    float z1 = b1[e1];
    float z2 = has2 ? b1[e2] : 0.0f;
    const float* xr  = x + (size_t)gr * D_DIM;
    const float* w1r = W1 + e1 * D_DIM;
    const float* w2r = W1 + (has2 ? e2 : 0) * D_DIM;
    #pragma unroll
    for (int d4 = 0; d4 < 25; ++d4) {
        float4 xv = reinterpret_cast<const float4*>(xr)[d4];
        float4 wa = reinterpret_cast<const float4*>(w1r)[d4];
        z1 = fmaf(xv.x, wa.x, z1); z1 = fmaf(xv.y, wa.y, z1);
        z1 = fmaf(xv.z, wa.z, z1); z1 = fmaf(xv.w, wa.w, z1);
        float4 wb = reinterpret_cast<const float4*>(w2r)[d4];
        z2 = fmaf(xv.x, wb.x, z2); z2 = fmaf(xv.y, wb.y, z2);
        z2 = fmaf(xv.z, wb.z, z2); z2 = fmaf(xv.w, wb.w, z2);
    }
    float h1 = fmaxf(z1, 0.0f);
    float h2 = fmaxf(z2, 0.0f);
    double dk[K_CODES];
    #pragma unroll
    for (int k = 0; k < K_CODES; ++k) {
        double p;
        {
            double dh = (double)h1 - (double)cb[k * D_DIM + e1];
            p = dh * dh;
        }
        if (has2) {
            double dh = (double)h2 - (double)cb[k * D_DIM + e2];
            p = fma(dh, dh, p);
        }
        for (int off = 32; off > 0; off >>= 1)
            p += __shfl_down(p, off);
        dk[k] = p;           // full sum valid in lane 0
    }
    int bi_ex = 0;
    double best = dk[0];
    #pragma unroll
    for (int k = 1; k < K_CODES; ++k)
        if (dk[k] < best) { best = dk[k]; bi_ex = k; }   // first-min tie-break
    return __shfl(bi_ex, 0);
}

// ---------------- Fused v6: barrier-free streaming MFMA GEMM + in-register VQ ----------------
// W1 hi/lo in swizzled LDS (ONE barrier). Each wave independently: 4x 16-row tiles,
// GEMM (h bit-identical to R8-R11), then f32 d2 via shfl_xor reduce, margin-guarded
// exact recompute (R6-proven), direct h/aux/payload stores, register loss partial.
__global__ __launch_bounds__(GEMM_TPB, 4) void fused_gemm_vq(
    const float* __restrict__ x, const float* __restrict__ W1,
    const float* __restrict__ b1, const float* __restrict__ cb,
    const int* __restrict__ qflag,
    float* __restrict__ out_h, float* __restrict__ out_pay,
    float* __restrict__ out_aux, double* __restrict__ partials)
{
    __shared__ unsigned short Bhi[NB_PAD * 128];   // 28 KB, swizzled
    __shared__ unsigned short Blo[NB_PAD * 128];   // 28 KB
    const int tid  = threadIdx.x;
    const int lane = tid & 63;
    const int wave = tid >> 6;
    const int rw = lane & 15;        // A row within 16x16 frag / B col within ct
    const int kp = lane >> 4;        // k sub-slice 0..3 / C row group

    // ---- stage W hi/lo into swizzled LDS (identical values to R8-R11 split) ----
    for (int i = tid; i < NB_PAD * 128; i += GEMM_TPB) {
        int n = i >> 7, k = i & 127;
        float w = (n < D_DIM && k < D_DIM) ? W1[n * D_DIM + k] : 0.0f;
        unsigned short hb = f2bf_rne(w);
        unsigned short lb = f2bf_rne(w - bf2f(hb));
        int byte = (n * 256 + k * 2) ^ ((n & 7) << 4);
        *reinterpret_cast<unsigned short*>(reinterpret_cast<char*>(Bhi) + byte) = hb;
        *reinterpret_cast<unsigned short*>(reinterpret_cast<char*>(Blo) + byte) = lb;
    }
    float bias[7];
    #pragma unroll
    for (int ct = 0; ct < 7; ++ct) {
        int n = ct * 16 + rw;
        bias[ct] = (n < D_DIM) ? b1[n] : 0.0f;
    }
    const int qz = *qflag;   // grid-uniform
    __syncthreads();         // THE one barrier; waves free-run after this

    const int wg = blockIdx.x * 8 + wave;   // global wave id 0..4095
    double loss_acc = 0.0;

    #pragma unroll 1
    for (int t = 0; t < TILES_PER_WAVE; ++t) {
        const int tile = wg + t * 4096;
        const float* base = x + (size_t)tile * 16 * D_DIM + rw * D_DIM;

        // ---- A f32 loads; kt=3 tail zero-filled (identical to R11) ----
        f32x4 f0[4], f1[4];
        #pragma unroll
        for (int kt = 0; kt < 3; ++kt) {
            const float* p = base + kt * 32 + kp * 8;
            f0[kt] = *reinterpret_cast<const f32x4*>(p);
            f1[kt] = *reinterpret_cast<const f32x4*>(p + 4);
        }
        if (kp == 0)
            f0[3] = *reinterpret_cast<const f32x4*>(base + 96);
        else
            f0[3] = (f32x4){0.f, 0.f, 0.f, 0.f};
        f1[3] = (f32x4){0.f, 0.f, 0.f, 0.f};

        // ---- in-register hi/lo cvt (identical to R8-R11) ----
        bf16x8 ah[4], al[4];
        #pragma unroll
        for (int kt = 0; kt < 4; ++kt) {
            #pragma unroll
            for (int i = 0; i < 4; ++i) {
                __bf16 h0 = (__bf16)f0[kt][i];
                ah[kt][i] = h0;
                al[kt][i] = (__bf16)(f0[kt][i] - (float)h0);
                __bf16 h1 = (__bf16)f1[kt][i];
                ah[kt][4 + i] = h1;
                al[kt][4 + i] = (__bf16)(f1[kt][i] - (float)h1);
            }
        }

        // ---- GEMM per col-tile (exact R11 chain order) + h store; keep acc live ----
        const int rb = tile * 16 + kp * 4;
        f32x4 acc[7];
        #pragma unroll
        for (int ct = 0; ct < 7; ++ct) {
            const int col = ct * 16 + rw;
            bf16x8 bhf[4], blf[4];
            #pragma unroll
            for (int kt = 0; kt < 4; ++kt) {
                int byte = (col * 256 + (kt * 32 + kp * 8) * 2) ^ ((col & 7) << 4);
                bhf[kt] = *reinterpret_cast<const bf16x8*>(
                    reinterpret_cast<const char*>(Bhi) + byte);
                blf[kt] = *reinterpret_cast<const bf16x8*>(
                    reinterpret_cast<const char*>(Blo) + byte);
            }
            f32x4 a = {0.f, 0.f, 0.f, 0.f};
            #pragma unroll
            for (int kt = 0; kt < 4; ++kt) {
                a = __builtin_amdgcn_mfma_f32_16x16x32_bf16(ah[kt], blf[kt], a, 0, 0, 0);
                a = __builtin_amdgcn_mfma_f32_16x16x32_bf16(al[kt], bhf[kt], a, 0, 0, 0);
                a = __builtin_amdgcn_mfma_f32_16x16x32_bf16(ah[kt], bhf[kt], a, 0, 0, 0);
            }
            acc[ct] = a;
            if (col < D_DIM) {
                #pragma unroll
                for (int i = 0; i < 4; ++i)
                    out_h[(size_t)(rb + i) * D_DIM + col] =
                        fmaxf(a[i] + bias[ct], 0.0f);
            }
        }

        if (qz) {
            // ---- f32 d2 partials: 4 rows x 4 codes, 7 dims per lane ----
            float s[4][K_CODES];
            #pragma unroll
            for (int i = 0; i < 4; ++i)
                #pragma unroll
                for (int k = 0; k < K_CODES; ++k) s[i][k] = 0.0f;
            #pragma unroll
            for (int ct = 0; ct < 7; ++ct) {
                const int col = ct * 16 + rw;
                float cc[K_CODES];
                #pragma unroll
                for (int k = 0; k < K_CODES; ++k)
                    cc[k] = (col < D_DIM) ? cb[k * D_DIM + col] : 0.0f;
                #pragma unroll
                for (int i = 0; i < 4; ++i) {
                    float h = fmaxf(acc[ct][i] + bias[ct], 0.0f);  // 0 for col>=100
                    #pragma unroll
                    for (int k = 0; k < K_CODES; ++k) {
                        float e = h - cc[k];
                        s[i][k] = fmaf(e, e, s[i][k]);
                    }
                }
            }
            // ---- reduce across the 16-lane rw group ----
            #pragma unroll
            for (int off = 1; off < 16; off <<= 1)
                #pragma unroll
                for (int i = 0; i < 4; ++i)
                    #pragma unroll
                    for (int k = 0; k < K_CODES; ++k)
                        s[i][k] += __shfl_xor(s[i][k], off);

            // ---- per-row argmin + margin flag ----
            int bi[4];
            int flg[4];
            #pragma unroll
            for (int i = 0; i < 4; ++i) {
                float best = s[i][0], second = 3.4e38f;
                int b = 0;
                #pragma unroll
                for (int k = 1; k < K_CODES; ++k) {
                    float v = s[i][k];
                    if (v < best) { second = best; best = v; b = k; }
                    else if (v < second) { second = v; }
                }
                bi[i] = b;
                flg[i] = (second - best) < TAU;
            }

            // ---- rare flagged rows: wave-serial exact recompute (R6-proven) ----
            #pragma unroll
            for (int i = 0; i < 4; ++i) {
                unsigned long long m = __ballot(flg[i] && rw == 0);
                while (m) {
                    int src = __ffsll((long long)m) - 1;
                    m &= m - 1;
                    int kpf = src >> 4;
                    int gr = tile * 16 + kpf * 4 + i;
                    int bx = exact_row_argmin(x, W1, b1, cb, gr, lane);
                    if (kp == kpf) bi[i] = bx;
                }
            }

            // ---- payload (float4 per kp-group) + loss partial ----
            if (rw == 0) {
                float4 pv = make_float4((float)bi[0], (float)bi[1],
                                        (float)bi[2], (float)bi[3]);
                *reinterpret_cast<float4*>(out_pay + tile * 16 + kp * 4) = pv;
                #pragma unroll
                for (int i = 0; i < 4; ++i)
                    loss_acc += (double)s[i][bi[i]];
            }

            // ---- aux = cb[bi] direct from registers (cb L1-hot; 64B groups) ----
            #pragma unroll
            for (int ct = 0; ct < 7; ++ct) {
                const int col = ct * 16 + rw;
                if (col < D_DIM) {
                    #pragma unroll
                    for (int i = 0; i < 4; ++i)
                        out_aux[(size_t)(rb + i) * D_DIM + col] =
                            cb[bi[i] * D_DIM + col];
                }
            }
        } else {
            if (rw == 0)
                *reinterpret_cast<float4*>(out_pay + tile * 16 + kp * 4) =
                    make_float4(0.f, 0.f, 0.f, 0.f);
            #pragma unroll
            for (int ct = 0; ct < 7; ++ct) {
                const int col = ct * 16 + rw;
                if (col < D_DIM) {
                    #pragma unroll
                    for (int i = 0; i < 4; ++i)
                        out_aux[(size_t)(rb + i) * D_DIM + col] = 0.0f;
                }
            }
        }
    }

    // ---- one loss store per wave (deterministic; only rw==0 lanes contributed) ----
    for (int off = 32; off > 0; off >>= 1)
        loss_acc += __shfl_down(loss_acc, off);
    if (lane == 0) partials[wg] = loss_acc;
}

// ---------------- deterministic final loss reduce (n = 4096 wave partials) ----------------
__global__ __launch_bounds__(256) void vq_final_kernel(
    const double* __restrict__ partials, int n, float* __restrict__ loss_out)
{
    __shared__ double sm[256];
    int tid = threadIdx.x;
    double s = 0.0;
    for (int i = tid; i < n; i += 256) s += partials[i];
    sm[tid] = s;
    __syncthreads();
    for (int off = 128; off > 0; off >>= 1) {
        if (tid < off) sm[tid] += sm[tid + off];
        __syncthreads();
    }
    if (tid == 0) {
        double mse = sm[0] / ((double)N_ROWS * (double)D_DIM);
        loss_out[0] = (float)(1.25 * mse);   // (1 + BETA) * mean((h-q)^2)
    }
}

extern "C" void kernel_launch(void* const* d_in, const int* in_sizes, int n_in,
                              void* d_out, int out_size, void* d_ws, size_t ws_size,
                              hipStream_t stream) {
    const float* x  = (const float*)d_in[0];
    const float* W1 = (const float*)d_in[1];
    const float* b1 = (const float*)d_in[2];
    const float* cb = (const float*)d_in[3];
    const int* qflag = (const int*)d_in[4];

    float* out = (float*)d_out;
    const int NR = in_sizes[0] / D_DIM;        // 262144 rows

    float* out_h    = out;                                  // [NR*100]
    float* out_pay  = out + (size_t)NR * D_DIM;             // [NR]
    float* out_aux  = out_pay + NR;                         // [NR*100]
    float* out_loss = out_aux + (size_t)NR * D_DIM;         // [1]
    double* partials = (double*)d_ws;                       // 4096 doubles

    fused_gemm_vq<<<GEMM_GRID, GEMM_TPB, 0, stream>>>(
        x, W1, b1, cb, qflag, out_h, out_pay, out_aux, partials);
    vq_final_kernel<<<1, 256, 0, stream>>>(partials, GEMM_GRID * 8, out_loss);
}